// Round 13
// baseline (198.715 us; speedup 1.0000x reference)
//
#include <hip/hip_runtime.h>
#include <stdint.h>

#define S_LEN 80
#define H_DIM 128
#define ROWS 10      // real lane rows per block (2560 = 256 blocks * 10)
#define MROWS 16     // padded MFMA M-tile
#define BLOCK_T 512  // 8 waves: wv 0-3 PROD (W_ih), wv 4-7 REC (W_hh + cell)

#define NL2E  (-1.44269504088896f)   // -log2(e)
#define N2L2E (-2.88539008177793f)   // -2*log2(e)

typedef __bf16 bf16x8 __attribute__((ext_vector_type(8)));
typedef unsigned short u16x8 __attribute__((ext_vector_type(8)));
typedef unsigned short u16x4 __attribute__((ext_vector_type(4)));
typedef float f32x4 __attribute__((ext_vector_type(4)));

__device__ __forceinline__ float sigy(float y) {
    return __builtin_amdgcn_rcpf(1.0f + __builtin_amdgcn_exp2f(y));
}
__device__ __forceinline__ float tanhy(float y) {
    return 2.0f * __builtin_amdgcn_rcpf(1.0f + __builtin_amdgcn_exp2f(y)) - 1.0f;
}
__device__ __forceinline__ unsigned short bfbits(float f) {
    return __builtin_bit_cast(unsigned short, (__bf16)f);   // HW RNE cvt
}

#define MFMA(A, B, C) __builtin_amdgcn_mfma_f32_16x16x32_bf16((A), (B), (C), 0, 0, 0)
#define WB(W) __builtin_bit_cast(bf16x8, W)

// R13 PRODUCER-CONSUMER WAVE SPECIALIZATION.
// PROD waves (wv<4): per step, xp[s+1] = bias + emb[s+1] @ W_ih^T for col
// group q=wv&3 (8 N-tiles = 32 MFMA) -> xp_lds (raw f32x4 fragment layout,
// linear per-lane b128 -> conflict-free, no transform) + emb[s+2] VALU.
// REC waves (wv>=4): gates = xp[s] + h[s] @ W_hh^T (32 MFMA) -> cell (8
// elems/lane, the trans-heavy part) -> h[s+1]. 1 PROD + 1 REC per SIMD ->
// REC's trans phase overlaps PROD's MFMA stream (cross-wave phase diversity
// that barrier-lockstep scheduling could never give: R5/R8/R10/R12 all ~117us).
// Both roles load into the SAME wgt[] array (role-selected source) -> one
// 128-AGPR allocation. Accumulation order bit-identical to R10 (xp is the
// C-input of the first hh MFMA). One barrier per step.
// Role-divergent single-copy bodies are safe (R11 precedent); the R6/R7
// miscompile was DUPLICATED bodies at the 256-reg cap.
//
// Swizzle discipline: key = (row&7)<<4 spans BITS 4-6 -> XOR onto the FULL
// logical byte offset (incl. kt*64, bits 6-7), never onto a pre-XORed base.
__global__ __launch_bounds__(BLOCK_T, 2)
void lane_lstm(const float* __restrict__ lanes,
               const float* __restrict__ W_emb, const float* __restrict__ b_emb,
               const float* __restrict__ W_ih,  const float* __restrict__ W_hh,
               const float* __restrict__ b_ih,  const float* __restrict__ b_hh,
               float* __restrict__ out, int BL)
{
    __shared__ __align__(16) float ext_lds[S_LEN * ROWS * 5];           // 16000 B
    __shared__ __align__(16) unsigned short emb_lds[2][MROWS * H_DIM];  // 2x4096 B
    __shared__ __align__(16) unsigned short h_lds[2][MROWS * H_DIM];    // 2x4096 B
    __shared__ __align__(16) float xp_lds[2 * 32 * 64 * 4];             // 65536 B
    __shared__ int valid_lds[MROWS];

    const int t    = threadIdx.x;
    const int lane = t & 63;
    const int wv   = t >> 6;
    const int role = wv >> 2;          // 0 = PROD, 1 = REC (wv and wv+4 share a SIMD)
    const int q    = wv & 3;           // col group: cols [q*32, q*32+32)
    const int row0 = blockIdx.x * ROWS;

    if (t < MROWS) valid_lds[t] = 1;
    {   // h0 = 0 (buffer 0)
        u16x4 z = {0, 0, 0, 0};
        *(u16x4*)((char*)&h_lds[0][0] + t * 8) = z;
    }
    __syncthreads();

    // ---- ext features (x,y,dx,dy,yaw) — all threads ----
    for (int p = t; p < S_LEN * ROWS; p += BLOCK_T) {
        int s = p / ROWS;
        int r = p - s * ROWS;
        int bl = row0 + r;
        float x = 0.f, y = 0.f, dx = 0.f, dy = 0.f;
        if (bl < BL) {
            const float* lp = lanes + ((size_t)s * BL + bl) * 2;
            x = lp[0]; y = lp[1];
            if (s > 0) {
                const float* lq = lanes + ((size_t)(s - 1) * BL + bl) * 2;
                dx = x - lq[0]; dy = y - lq[1];
            }
            if (__builtin_isnan(x) || __builtin_isnan(y)) valid_lds[r] = 0;
        }
        float* e = &ext_lds[p * 5];
        e[0] = x; e[1] = y; e[2] = dx; e[3] = dy; e[4] = atan2f(y, x);
    }

    // ---- weight B-frags: SAME array, role-selected source (one AGPR alloc) ----
    // frag: col = g*128 + q*32 + nt*16 + (lane&15), k = kt*32 + (lane>>4)*8 + j.
    // Gate scale: i,f,o -> -log2e ; g -> -2log2e (exp2-direct nonlinearities).
    const float* Wsrc = role ? W_hh : W_ih;
    const int kb0 = (lane >> 4) << 3;
    f32x4 wgt[4][2][4];     // [g][nt][kt] = 32 frags = 128 AGPR
    float bsc[4][2];        // bias*scale per (g,nt) — consumed by PROD only
    #pragma unroll
    for (int g = 0; g < 4; ++g) {
        const float sc = (g == 2) ? N2L2E : NL2E;
        #pragma unroll
        for (int nt = 0; nt < 2; ++nt) {
            const int col = g * H_DIM + q * 32 + nt * 16 + (lane & 15);
            bsc[g][nt] = (b_ih[col] + b_hh[col]) * sc;
            #pragma unroll
            for (int kt = 0; kt < 4; ++kt) {
                const float* pw = Wsrc + (size_t)col * H_DIM + kt * 32 + kb0;
                u16x8 tw;
                #pragma unroll
                for (int j = 0; j < 8; ++j) tw[j] = bfbits(pw[j] * sc);
                wgt[g][nt][kt] = __builtin_bit_cast(f32x4, tw);
            }
        }
    }
    #pragma unroll
    for (int g = 0; g < 4; ++g)
        #pragma unroll
        for (int nt = 0; nt < 2; ++nt)
            #pragma unroll
            for (int kt = 0; kt < 4; ++kt)
                asm volatile("" : "+a"(wgt[g][nt][kt]));   // pin to AGPR file

    // ---- emb constants: PROD threads (t<256) cover rows {er2, er2+8} x 4 cols ----
    const int er2 = (t >> 5) & 7;
    const int ec0 = (t & 31) << 2;
    float wemb[4][5], bemb[4];
    #pragma unroll
    for (int j = 0; j < 4; ++j) {
        #pragma unroll
        for (int d = 0; d < 5; ++d) wemb[j][d] = W_emb[(ec0 + j) * 5 + d];
        bemb[j] = b_emb[ec0 + j];
    }

    auto emb_store = [&](int sx, int b) {   // called by PROD threads only
        #pragma unroll
        for (int rr = 0; rr < 2; ++rr) {
            const int r = er2 + rr * 8;
            float x0 = 0.f, x1 = 0.f, x2 = 0.f, x3 = 0.f, x4 = 0.f;
            if (r < ROWS && valid_lds[r] && row0 + r < BL) {
                const float* e = &ext_lds[(sx * ROWS + r) * 5];
                x0 = e[0]; x1 = e[1]; x2 = e[2]; x3 = e[3]; x4 = e[4];
            }
            u16x4 ev;
            #pragma unroll
            for (int j = 0; j < 4; ++j) {
                float a = bemb[j];
                a += wemb[j][0] * x0; a += wemb[j][1] * x1; a += wemb[j][2] * x2;
                a += wemb[j][3] * x3; a += wemb[j][4] * x4;
                ev[j] = bfbits(fmaxf(a, 0.f));
            }
            const int byte = ((r << 8) + (ec0 << 1)) ^ ((r & 7) << 4);
            *(u16x4*)((char*)&emb_lds[b][0] + byte) = ev;
        }
    };

    // A-frag addressing (both roles): row = lane&15, full-offset XOR.
    const int arow  = lane & 15;
    const int akey  = (arow & 7) << 4;
    const int abase = (arow << 8) + ((lane >> 4) << 4);
    const int crow  = (lane >> 4) << 2;     // C/D (m89): row=(lane>>4)*4+i, col=lane&15
    // xp hand-off: [b][q*8 + g*2 + nt][lane] f32x4, linear per lane.
    const int xpbase = q * 8192 + lane * 16;

    __syncthreads();       // ext + valid ready
    if (!role) emb_store(0, 0);
    __syncthreads();       // emb[0] visible
    if (!role) {
        // xp[0] -> buffer 0
        const char* eb = (const char*)&emb_lds[0][0];
        bf16x8 ae0 = *(const bf16x8*)(eb + ((abase + 0 * 64) ^ akey));
        bf16x8 ae1 = *(const bf16x8*)(eb + ((abase + 1 * 64) ^ akey));
        bf16x8 ae2 = *(const bf16x8*)(eb + ((abase + 2 * 64) ^ akey));
        bf16x8 ae3 = *(const bf16x8*)(eb + ((abase + 3 * 64) ^ akey));
        #pragma unroll
        for (int g = 0; g < 4; ++g) {
            #pragma unroll
            for (int nt = 0; nt < 2; ++nt) {
                f32x4 a;
                a[0] = bsc[g][nt]; a[1] = bsc[g][nt]; a[2] = bsc[g][nt]; a[3] = bsc[g][nt];
                a = MFMA(ae0, WB(wgt[g][nt][0]), a);
                a = MFMA(ae1, WB(wgt[g][nt][1]), a);
                a = MFMA(ae2, WB(wgt[g][nt][2]), a);
                a = MFMA(ae3, WB(wgt[g][nt][3]), a);
                *(f32x4*)((char*)&xp_lds[0] + xpbase + (g * 2 + nt) * 1024) = a;
            }
        }
        emb_store(1, 1);
    }
    __syncthreads();       // xp[0] + emb[1] visible

    float c[2][4] = {{0.f, 0.f, 0.f, 0.f}, {0.f, 0.f, 0.f, 0.f}};   // REC state

    for (int s = 0; s < S_LEN - 1; ++s) {
        if (!role) {
            // ---- PROD: xp[s+1] from emb[s+1]; then emb[s+2] ----
            const char* en = (const char*)&emb_lds[(s + 1) & 1][0];
            bf16x8 ae0 = *(const bf16x8*)(en + ((abase + 0 * 64) ^ akey));
            bf16x8 ae1 = *(const bf16x8*)(en + ((abase + 1 * 64) ^ akey));
            bf16x8 ae2 = *(const bf16x8*)(en + ((abase + 2 * 64) ^ akey));
            bf16x8 ae3 = *(const bf16x8*)(en + ((abase + 3 * 64) ^ akey));
            char* xw = (char*)&xp_lds[0] + ((s + 1) & 1) * 32768 + xpbase;
            #pragma unroll
            for (int g = 0; g < 4; ++g) {
                #pragma unroll
                for (int nt = 0; nt < 2; ++nt) {
                    f32x4 a;
                    a[0] = bsc[g][nt]; a[1] = bsc[g][nt]; a[2] = bsc[g][nt]; a[3] = bsc[g][nt];
                    a = MFMA(ae0, WB(wgt[g][nt][0]), a);
                    a = MFMA(ae1, WB(wgt[g][nt][1]), a);
                    a = MFMA(ae2, WB(wgt[g][nt][2]), a);
                    a = MFMA(ae3, WB(wgt[g][nt][3]), a);
                    *(f32x4*)(xw + (g * 2 + nt) * 1024) = a;
                }
            }
            if (s + 2 < S_LEN) emb_store(s + 2, s & 1);
        } else {
            // ---- REC: gates = xp[s] + h[s] @ W_hh^T; cell; h[s+1] ----
            const char* hb = (const char*)&h_lds[s & 1][0];
            const char* xr = (const char*)&xp_lds[0] + (s & 1) * 32768 + xpbase;
            bf16x8 ah0 = *(const bf16x8*)(hb + ((abase + 0 * 64) ^ akey));
            bf16x8 ah1 = *(const bf16x8*)(hb + ((abase + 1 * 64) ^ akey));
            bf16x8 ah2 = *(const bf16x8*)(hb + ((abase + 2 * 64) ^ akey));
            bf16x8 ah3 = *(const bf16x8*)(hb + ((abase + 3 * 64) ^ akey));
            f32x4 ga[4][2];
            #pragma unroll
            for (int g = 0; g < 4; ++g)
                #pragma unroll
                for (int nt = 0; nt < 2; ++nt)
                    ga[g][nt] = *(const f32x4*)(xr + (g * 2 + nt) * 1024);
            #pragma unroll
            for (int g = 0; g < 4; ++g) {
                #pragma unroll
                for (int nt = 0; nt < 2; ++nt) {
                    ga[g][nt] = MFMA(ah0, WB(wgt[g][nt][0]), ga[g][nt]);
                    ga[g][nt] = MFMA(ah1, WB(wgt[g][nt][1]), ga[g][nt]);
                    ga[g][nt] = MFMA(ah2, WB(wgt[g][nt][2]), ga[g][nt]);
                    ga[g][nt] = MFMA(ah3, WB(wgt[g][nt][3]), ga[g][nt]);
                }
            }
            char* hn = (char*)&h_lds[(s + 1) & 1][0];
            #pragma unroll
            for (int nt = 0; nt < 2; ++nt) {
                #pragma unroll
                for (int i = 0; i < 4; ++i) {
                    float cc = sigy(ga[1][nt][i]) * c[nt][i]
                             + sigy(ga[0][nt][i]) * tanhy(ga[2][nt][i]);
                    c[nt][i] = cc;
                    const float hv = sigy(ga[3][nt][i]) * tanhy(cc * N2L2E);
                    const int r  = crow + i;
                    const int hc = q * 32 + nt * 16 + (lane & 15);
                    const int byte = ((r << 8) + (hc << 1)) ^ ((r & 7) << 4);
                    *(unsigned short*)(hn + byte) = bfbits(hv);
                }
            }
        }
        __syncthreads();   // one barrier/step
    }

    // ---- peeled final step s = 79 (REC only): hh + cell + global out ----
    if (role) {
        const int s = S_LEN - 1;
        const char* hb = (const char*)&h_lds[s & 1][0];
        const char* xr = (const char*)&xp_lds[0] + (s & 1) * 32768 + xpbase;
        bf16x8 ah0 = *(const bf16x8*)(hb + ((abase + 0 * 64) ^ akey));
        bf16x8 ah1 = *(const bf16x8*)(hb + ((abase + 1 * 64) ^ akey));
        bf16x8 ah2 = *(const bf16x8*)(hb + ((abase + 2 * 64) ^ akey));
        bf16x8 ah3 = *(const bf16x8*)(hb + ((abase + 3 * 64) ^ akey));
        f32x4 ga[4][2];
        #pragma unroll
        for (int g = 0; g < 4; ++g)
            #pragma unroll
            for (int nt = 0; nt < 2; ++nt)
                ga[g][nt] = *(const f32x4*)(xr + (g * 2 + nt) * 1024);
        #pragma unroll
        for (int g = 0; g < 4; ++g) {
            #pragma unroll
            for (int nt = 0; nt < 2; ++nt) {
                ga[g][nt] = MFMA(ah0, WB(wgt[g][nt][0]), ga[g][nt]);
                ga[g][nt] = MFMA(ah1, WB(wgt[g][nt][1]), ga[g][nt]);
                ga[g][nt] = MFMA(ah2, WB(wgt[g][nt][2]), ga[g][nt]);
                ga[g][nt] = MFMA(ah3, WB(wgt[g][nt][3]), ga[g][nt]);
            }
        }
        #pragma unroll
        for (int nt = 0; nt < 2; ++nt) {
            #pragma unroll
            for (int i = 0; i < 4; ++i) {
                float cc = sigy(ga[1][nt][i]) * c[nt][i]
                         + sigy(ga[0][nt][i]) * tanhy(ga[2][nt][i]);
                const float hv = sigy(ga[3][nt][i]) * tanhy(cc * N2L2E);
                const int r  = crow + i;
                const int hc = q * 32 + nt * 16 + (lane & 15);
                if (r < ROWS && row0 + r < BL)
                    out[(size_t)(row0 + r) * H_DIM + hc] = hv;
            }
        }
    }
}

extern "C" void kernel_launch(void* const* d_in, const int* in_sizes, int n_in,
                              void* d_out, int out_size, void* d_ws, size_t ws_size,
                              hipStream_t stream) {
    const float* lanes = (const float*)d_in[1];
    const float* W_emb = (const float*)d_in[2];
    const float* b_emb = (const float*)d_in[3];
    const float* W_ih  = (const float*)d_in[4];
    const float* W_hh  = (const float*)d_in[5];
    const float* b_ih  = (const float*)d_in[6];
    const float* b_hh  = (const float*)d_in[7];
    float* out = (float*)d_out;

    const int BL   = in_sizes[1] / (2 * S_LEN);   // 2560
    const int grid = (BL + ROWS - 1) / ROWS;      // 256 blocks -> 1 per CU

    lane_lstm<<<dim3(grid), dim3(BLOCK_T), 0, stream>>>(
        lanes, W_emb, b_emb, W_ih, W_hh, b_ih, b_hh, out, BL);
}